// Round 1
// baseline (2017.299 us; speedup 1.0000x reference)
//
#include <hip/hip_runtime.h>
#include <hip/hip_cooperative_groups.h>
#include <cmath>

namespace cg = cooperative_groups;

#define IN_CH 128

// Monotone descending key: smaller key == higher norm; ties -> smaller edge idx.
__device__ __forceinline__ unsigned long long make_key(float norm, int e) {
    unsigned int b = __float_as_uint(norm);
    unsigned int asc = (b & 0x80000000u) ? ~b : (b | 0x80000000u); // ascending monotone map
    unsigned int desc = ~asc;
    return (((unsigned long long)desc) << 32) | (unsigned int)e;
}

__global__ void init_kernel(unsigned int* node_max, double* denom, int* matched,
                            unsigned long long* best0, unsigned long long* best1,
                            int* cluster, int* partner, float* s_rep, int* counters, int N) {
    int i = blockIdx.x * blockDim.x + threadIdx.x;
    if (i < N) {
        node_max[i] = 0u;          // bits of +0.0f; any positive score has bits > 0
        denom[i]    = 0.0;
        matched[i]  = 0;
        best0[i]    = ~0ULL;
        best1[i]    = ~0ULL;
        cluster[i]  = i;
        partner[i]  = i;
        s_rep[i]    = 1.0f;
    }
    if (i < 2) counters[i] = 0;
}

// One wave per node: p[n] = dot(x[n], w_src), q[n] = dot(x[n], w_dst), double accum.
__global__ void proj_kernel(const float* __restrict__ x, const float* __restrict__ w_src,
                            const float* __restrict__ w_dst, float* __restrict__ p,
                            float* __restrict__ q, int N) {
    int wave = (blockIdx.x * blockDim.x + threadIdx.x) >> 6;
    int lane = threadIdx.x & 63;
    if (wave >= N) return;
    float2 xv = ((const float2*)(x + (size_t)wave * IN_CH))[lane];
    float2 ws = ((const float2*)w_src)[lane];
    float2 wd = ((const float2*)w_dst)[lane];
    double ap = (double)xv.x * (double)ws.x + (double)xv.y * (double)ws.y;
    double aq = (double)xv.x * (double)wd.x + (double)xv.y * (double)wd.y;
    #pragma unroll
    for (int off = 32; off > 0; off >>= 1) {
        ap += __shfl_down(ap, off);
        aq += __shfl_down(aq, off);
    }
    if (lane == 0) { p[wave] = (float)ap; q[wave] = (float)aq; }
}

__global__ void score_kernel(const int* __restrict__ row, const int* __restrict__ col,
                             const float* __restrict__ p, const float* __restrict__ q,
                             const float* __restrict__ bptr, float* __restrict__ score,
                             unsigned int* __restrict__ node_max, int E) {
    int e = blockIdx.x * blockDim.x + threadIdx.x;
    if (e >= E) return;
    float s = p[row[e]] + q[col[e]] + bptr[0];
    score[e] = s;
    if (s > 0.0f) atomicMax(&node_max[row[e]], __float_as_uint(s));
}

__global__ void exp_kernel(const int* __restrict__ row, const float* __restrict__ score,
                           const unsigned int* __restrict__ node_max, float* __restrict__ norm,
                           double* __restrict__ denom, int E) {
    int e = blockIdx.x * blockDim.x + threadIdx.x;
    if (e >= E) return;
    int u = row[e];
    unsigned int mb = node_max[u];
    float s = score[e];
    float ev = 0.0f;
    if (mb != 0u && s > 0.0f) {
        float m = __uint_as_float(mb);
        ev = (float)exp((double)(s - m));   // double exp ~correctly rounded
        atomicAdd(&denom[u], (double)ev);   // order-independent (double accum)
    }
    norm[e] = ev;  // exp value for now; finalized in norm_kernel
}

__global__ void norm_kernel(const int* __restrict__ row, const float* __restrict__ score,
                            const unsigned int* __restrict__ node_max,
                            const double* __restrict__ denom, float* __restrict__ norm,
                            unsigned long long* __restrict__ key, int E) {
    int e = blockIdx.x * blockDim.x + threadIdx.x;
    if (e >= E) return;
    int u = row[e];
    unsigned int mb = node_max[u];
    float nv;
    if (mb != 0u) {
        float s = score[e];
        if (s > 0.0f) {
            float d = (float)denom[u];      // denom>0 guaranteed here
            nv = norm[e] / d + 0.5f;        // exact f32 div + add, same as ref
        } else {
            nv = 0.0f;
        }
    } else {
        nv = score[e];                       // raw score for rows with no positive edge
    }
    norm[e] = nv;
    key[e] = make_key(nv, e);
}

struct MatchParams {
    const int* row; const int* col;
    const unsigned long long* key; const float* norm;
    int* matched; unsigned long long* best0; unsigned long long* best1;
    int* list0; int* list1; int* counters;
    int* cluster; int* partner; float* s_rep;
    int E; int N;
};

// Locally-dominant matching == sequential greedy matching under strict total order.
__global__ void __launch_bounds__(256, 1) match_kernel(MatchParams P) {
    cg::grid_group grid = cg::this_grid();
    const long long gtid = blockIdx.x * blockDim.x + threadIdx.x;
    const long long gsz  = (long long)gridDim.x * blockDim.x;
    long long n_in = P.E;
    for (int round = 0; round < 2000; ++round) {
        int pp = round & 1;
        unsigned long long* bcur  = pp ? P.best1 : P.best0;
        unsigned long long* bnext = pp ? P.best0 : P.best1;
        const int* lin = pp ? P.list1 : P.list0;
        int* lout      = pp ? P.list0 : P.list1;
        int* cnt_out   = &P.counters[1 - pp];

        // Phase A: scatter-min priorities of live edges into node slots.
        if (gtid == 0) *cnt_out = 0;
        for (long long i = gtid; i < n_in; i += gsz) {
            int e = (round == 0) ? (int)i : lin[i];
            int u = P.row[e], v = P.col[e];
            if (u == v) continue;
            if (P.matched[u] | P.matched[v]) continue;
            unsigned long long k = P.key[e];
            atomicMin(&bcur[u], k);
            atomicMin(&bcur[v], k);
        }
        grid.sync();

        // Phase B: select winners (min at both endpoints), compact survivors,
        // reset the other best-buffer for next round.
        for (long long i = gtid; i < n_in; i += gsz) {
            int e = (round == 0) ? (int)i : lin[i];
            int u = P.row[e], v = P.col[e];
            if (u == v) continue;
            if (P.matched[u] | P.matched[v]) continue;   // benign race: conservative
            unsigned long long k = P.key[e];
            if (bcur[u] == k && bcur[v] == k) {
                P.matched[u] = 1; P.matched[v] = 1;
                P.cluster[v] = u;
                P.partner[u] = v;
                P.s_rep[u]   = P.norm[e];
            } else {
                int pos = atomicAdd(cnt_out, 1);
                lout[pos] = e;
            }
        }
        for (long long i = gtid; i < P.N; i += gsz) bnext[i] = ~0ULL;
        grid.sync();

        n_in = P.counters[1 - pp];
        if (n_in == 0) break;
    }
}

__global__ void newx_kernel(const float* __restrict__ x, const int* __restrict__ cluster,
                            const int* __restrict__ matched, const int* __restrict__ partner,
                            const float* __restrict__ s_rep, float* __restrict__ out, int N) {
    int t = blockIdx.x * blockDim.x + threadIdx.x;
    if (t >= N * (IN_CH / 4)) return;
    int n = t >> 5;            // IN_CH/4 == 32 float4 per node
    int c = (t & 31) * 4;
    float4 o;
    int cl = cluster[n];
    if (cl != n) {
        o = make_float4(0.f, 0.f, 0.f, 0.f);              // merged-away node row
    } else if (matched[n]) {
        int v = partner[n];
        float s = s_rep[n];
        float4 xu = *(const float4*)(x + (size_t)n * IN_CH + c);
        float4 xv = *(const float4*)(x + (size_t)v * IN_CH + c);
        o.x = (xu.x + xv.x) * s + xv.x;
        o.y = (xu.y + xv.y) * s + xv.y;
        o.z = (xu.z + xv.z) * s + xv.z;
        o.w = (xu.w + xv.w) * s + xv.w;
    } else {
        o = *(const float4*)(x + (size_t)n * IN_CH + c);  // untouched node
    }
    ((float4*)out)[t] = o;
}

__global__ void nodeout_kernel(const int* __restrict__ cluster, float* __restrict__ out_cluster,
                               float* __restrict__ out_isrep, int N) {
    int i = blockIdx.x * blockDim.x + threadIdx.x;
    if (i >= N) return;
    int cl = cluster[i];
    out_cluster[i] = (float)cl;
    out_isrep[i]   = (cl == i) ? 1.0f : 0.0f;
}

__global__ void edges_kernel(const int* __restrict__ row, const int* __restrict__ col,
                             const float* __restrict__ w, const int* __restrict__ cluster,
                             float* __restrict__ out_nrow, float* __restrict__ out_ncol,
                             float* __restrict__ out_valid, float* __restrict__ out_w, int E) {
    int e = blockIdx.x * blockDim.x + threadIdx.x;
    if (e >= E) return;
    int nr = cluster[row[e]];
    int nc = cluster[col[e]];
    out_nrow[e]  = (float)nr;
    out_ncol[e]  = (float)nc;
    out_valid[e] = (nr != nc) ? 1.0f : 0.0f;
    out_w[e]     = w[e];
}

extern "C" void kernel_launch(void* const* d_in, const int* in_sizes, int n_in_args,
                              void* d_out, int out_size, void* d_ws, size_t ws_size,
                              hipStream_t stream) {
    const float* x     = (const float*)d_in[0];
    const float* w_src = (const float*)d_in[1];
    const float* w_dst = (const float*)d_in[2];
    const float* bptr  = (const float*)d_in[3];
    const int*   ei    = (const int*)d_in[4];
    const float* ew    = (const float*)d_in[5];
    const int N = in_sizes[0] / IN_CH;
    const int E = in_sizes[5];
    const int* row = ei;
    const int* col = ei + E;

    // Workspace carve (re-poisoned each call; everything initialized by kernels)
    char* ws = (char*)d_ws;
    size_t off = 0;
    auto alloc = [&](size_t bytes) -> void* {
        off = (off + 255) & ~(size_t)255;
        void* ptr = ws + off;
        off += bytes;
        return ptr;
    };
    float*              score    = (float*)alloc((size_t)E * 4);
    float*              norm     = (float*)alloc((size_t)E * 4);
    unsigned long long* key      = (unsigned long long*)alloc((size_t)E * 8);
    int*                list0    = (int*)alloc((size_t)E * 4);
    int*                list1    = (int*)alloc((size_t)E * 4);
    unsigned int*       node_max = (unsigned int*)alloc((size_t)N * 4);
    double*             denom    = (double*)alloc((size_t)N * 8);
    int*                matched  = (int*)alloc((size_t)N * 4);
    unsigned long long* best0    = (unsigned long long*)alloc((size_t)N * 8);
    unsigned long long* best1    = (unsigned long long*)alloc((size_t)N * 8);
    int*                cluster  = (int*)alloc((size_t)N * 4);
    int*                partner  = (int*)alloc((size_t)N * 4);
    float*              s_rep    = (float*)alloc((size_t)N * 4);
    float*              pbuf     = (float*)alloc((size_t)N * 4);
    float*              qbuf     = (float*)alloc((size_t)N * 4);
    int*                counters = (int*)alloc(64);

    // Output layout: new_x[N*128] | cluster[N] | is_rep[N] | new_row[E] | new_col[E] | edge_valid[E] | edge_weight[E]
    float* out       = (float*)d_out;
    float* o_newx    = out;
    float* o_cluster = out + (size_t)N * IN_CH;
    float* o_isrep   = o_cluster + N;
    float* o_nrow    = o_isrep + N;
    float* o_ncol    = o_nrow + E;
    float* o_valid   = o_ncol + E;
    float* o_w       = o_valid + E;

    const int T = 256;
    hipLaunchKernelGGL(init_kernel, dim3((N + T - 1) / T), dim3(T), 0, stream,
                       node_max, denom, matched, best0, best1, cluster, partner, s_rep, counters, N);
    hipLaunchKernelGGL(proj_kernel, dim3((N * 64 + T - 1) / T), dim3(T), 0, stream,
                       x, w_src, w_dst, pbuf, qbuf, N);
    hipLaunchKernelGGL(score_kernel, dim3((E + T - 1) / T), dim3(T), 0, stream,
                       row, col, pbuf, qbuf, bptr, score, node_max, E);
    hipLaunchKernelGGL(exp_kernel, dim3((E + T - 1) / T), dim3(T), 0, stream,
                       row, score, node_max, norm, denom, E);
    hipLaunchKernelGGL(norm_kernel, dim3((E + T - 1) / T), dim3(T), 0, stream,
                       row, score, node_max, denom, norm, key, E);

    MatchParams P{row, col, key, norm, matched, best0, best1,
                  list0, list1, counters, cluster, partner, s_rep, E, N};
    void* args[] = {&P};
    hipLaunchCooperativeKernel((const void*)match_kernel, dim3(256), dim3(256), args, 0, stream);

    hipLaunchKernelGGL(newx_kernel, dim3((N * 32 + T - 1) / T), dim3(T), 0, stream,
                       x, cluster, matched, partner, s_rep, o_newx, N);
    hipLaunchKernelGGL(nodeout_kernel, dim3((N + T - 1) / T), dim3(T), 0, stream,
                       cluster, o_cluster, o_isrep, N);
    hipLaunchKernelGGL(edges_kernel, dim3((E + T - 1) / T), dim3(T), 0, stream,
                       row, col, ew, cluster, o_nrow, o_ncol, o_valid, o_w, E);
}